// Round 10
// baseline (230.956 us; speedup 1.0000x reference)
//
#include <hip/hip_runtime.h>

#define B_   8
#define C_   128
#define N_   4096
#define C2_  64

typedef __bf16 bf16x8 __attribute__((ext_vector_type(8)));
typedef float  f32x4  __attribute__((ext_vector_type(4)));

#define MFMA16(a, b, c) __builtin_amdgcn_mfma_f32_16x16x32_bf16((a), (b), (c), 0, 0, 0)

// sqrt(log2(e)): fold into q/k so softmax uses exp2 directly (E' = E * log2e)
#define QK_SCALE 1.2011224087864498f

static __device__ __forceinline__ unsigned short f2bf(float f) {
    union { __bf16 b; unsigned short u; } cv;
    cv.b = (__bf16)f;
    return cv.u;
}
static __device__ __forceinline__ float bf2f(unsigned short u) {
    union { unsigned int u; float f; } cv;
    cv.u = ((unsigned int)u) << 16;
    return cv.f;
}

struct us4 { unsigned short a, b, c, d; };

// async global->LDS, 16 B per lane.  LDS dest must be linear in lane order.
static __device__ __forceinline__ void gl_lds16(const unsigned short* g, void* l) {
    __builtin_amdgcn_global_load_lds(
        (const __attribute__((address_space(1))) unsigned int*)g,
        (__attribute__((address_space(3))) unsigned int*)l,
        16, 0, 0);
}

// ---------------------------------------------------------------------------
// K1: fused projection GEMM.  D[192 o][64 n] = W(3x64 stacked)[o][c] * x[c][n]
//     per (b, 64-n tile).  Also zeros the rowsum accumulator for k2's atomics.
// ---------------------------------------------------------------------------
__global__ __launch_bounds__(256) void k1_proj(
    const float* __restrict__ x, const float* __restrict__ w_qk,
    const float* __restrict__ w_v, const float* __restrict__ b_v,
    const float* __restrict__ w_x,
    unsigned short* __restrict__ qk_t, unsigned short* __restrict__ xv_bf,
    float* __restrict__ xc, float* __restrict__ rowsum)
{
    __shared__ __align__(16) unsigned short w_lds[192 * 136];
    __shared__ __align__(16) unsigned short x_t[64 * 136];
    const int tid = threadIdx.x;
    const int wave = tid >> 6, lane = tid & 63;
    const int quad = lane >> 4, col = lane & 15;
    const int b = blockIdx.y;
    const int n0 = blockIdx.x * 64;

    // zero rowsum accumulator: 512 blocks x 64 floats = 32768
    if (tid < 64) rowsum[(blockIdx.y * 64 + blockIdx.x) * 64 + tid] = 0.f;

    const float* wsrc[3] = {w_qk, w_v, w_x};
    #pragma unroll
    for (int mat = 0; mat < 3; ++mat) {
        const float* wm = wsrc[mat];
        #pragma unroll
        for (int it = 0; it < 8; ++it) {
            const int idx = it * 256 + tid;            // [0, 2048)
            const int o = idx >> 5, c = (idx & 31) * 4;
            const float4 v = *(const float4*)(wm + o * C_ + c);
            us4 pk;
            pk.a = f2bf(v.x); pk.b = f2bf(v.y); pk.c = f2bf(v.z); pk.d = f2bf(v.w);
            *(us4*)&w_lds[(mat * 64 + o) * 136 + c] = pk;
        }
    }
    const float* xb = x + (size_t)b * C_ * N_ + n0;
    #pragma unroll
    for (int it = 0; it < 8; ++it) {
        const int idx = it * 256 + tid;                // [0, 2048)
        const int c = idx >> 4, n = (idx & 15) * 4;
        const float4 v = *(const float4*)(xb + (size_t)c * N_ + n);
        x_t[(n + 0) * 136 + c] = f2bf(v.x);
        x_t[(n + 1) * 136 + c] = f2bf(v.y);
        x_t[(n + 2) * 136 + c] = f2bf(v.z);
        x_t[(n + 3) * 136 + c] = f2bf(v.w);
    }
    __syncthreads();

    const int nw = wave * 16;
    bf16x8 bfr[4];
    #pragma unroll
    for (int kt = 0; kt < 4; ++kt)
        bfr[kt] = *(const bf16x8*)&x_t[(nw + col) * 136 + kt * 32 + quad * 8];

    const int n_g = n0 + nw + col;

    #pragma unroll
    for (int ot = 0; ot < 12; ++ot) {
        f32x4 acc = {0.f, 0.f, 0.f, 0.f};
        #pragma unroll
        for (int kt = 0; kt < 4; ++kt) {
            const bf16x8 afr = *(const bf16x8*)&w_lds[(ot * 16 + col) * 136 + kt * 32 + quad * 8];
            acc = MFMA16(afr, bfr[kt], acc);
        }
        if (ot < 4) {
            us4 pk;
            pk.a = f2bf(acc[0] * QK_SCALE); pk.b = f2bf(acc[1] * QK_SCALE);
            pk.c = f2bf(acc[2] * QK_SCALE); pk.d = f2bf(acc[3] * QK_SCALE);
            *(us4*)&qk_t[(size_t)(b * N_ + n_g) * C2_ + ot * 16 + quad * 4] = pk;
        } else if (ot < 8) {
            const float4 bv4 = *(const float4*)(b_v + (ot - 4) * 16 + quad * 4);
            const float* bvp = (const float*)&bv4;
            #pragma unroll
            for (int r = 0; r < 4; ++r)
                xv_bf[(size_t)(b * C2_ + (ot - 4) * 16 + quad * 4 + r) * N_ + n_g]
                    = f2bf(acc[r] + bvp[r]);
        } else {
            #pragma unroll
            for (int r = 0; r < 4; ++r)
                xc[(size_t)(b * C2_ + (ot - 8) * 16 + quad * 4 + r) * N_ + n_g] = acc[r];
        }
    }
}

// ---------------------------------------------------------------------------
// K2: row softmax sums exploiting E = Q^T Q symmetry.  Only upper-triangle
//     256x256 tile pairs (ti <= tj) are computed: each exp2 value feeds
//     rowsum over its rows (row-dir) AND, when ti != tj, rowsum over its
//     columns (col-dir, covering E[m][n] by symmetry).  53% of full E work.
//     Grid 1088: b=id&7, pair p=id>>3 in [0,136).  atomicAdd into rowsum.
// ---------------------------------------------------------------------------
__global__ __launch_bounds__(256) void k2_rowstats(
    const unsigned short* __restrict__ qk_t, float* __restrict__ rowsum)
{
    __shared__ __align__(16) unsigned char lds_raw[2 * 16384];
    const int tid = threadIdx.x;
    const int wave = tid >> 6, lane = tid & 63;
    const int quad = lane >> 4, col = lane & 15;
    const int b = blockIdx.x & 7;
    // triangle decode: p -> (ti, tj), ti <= tj, T = 16
    int ti = 0, rem = blockIdx.x >> 3;
    while (rem >= 16 - ti) { rem -= 16 - ti; ++ti; }
    const int tj = ti + rem;
    const int n_base = ti * 256 + wave * 64;
    const int m_base = tj * 256;
    const unsigned short* qb = qk_t + (size_t)b * N_ * C2_;
    float* rsb = rowsum + b * N_;

    // four persistent A-frag sets: rows n_base + s*16 + col
    bf16x8 a0[4], a1[4];
    #pragma unroll
    for (int s = 0; s < 4; ++s) {
        const unsigned short* p = qb + (size_t)(n_base + s * 16 + col) * C2_ + quad * 8;
        a0[s] = *(const bf16x8*)p;
        a1[s] = *(const bf16x8*)(p + 32);
    }

    // stage 128 m-rows (16 KB) into buffer p
    auto stage = [&](int m0, int p) {
        unsigned char* base = lds_raw + p * 16384;
        #pragma unroll
        for (int r = 0; r < 4; ++r) {
            const int idx = r * 256 + tid;             // [0, 1024)
            const int row = idx >> 3, seg = idx & 7;
            gl_lds16(qb + (size_t)(m0 + row) * C2_ + (size_t)(seg ^ (row & 7)) * 8,
                     base + idx * 16);
        }
    };

    float rs[4][4];
    #pragma unroll
    for (int s = 0; s < 4; ++s)
        #pragma unroll
        for (int r = 0; r < 4; ++r) rs[s][r] = 0.f;
    float cp[16];
    #pragma unroll
    for (int g = 0; g < 16; ++g) cp[g] = 0.f;

    stage(m_base, 0);
    __syncthreads();

    for (int c = 0; c < 2; ++c) {
        if (c == 0) stage(m_base + 128, 1);
        const unsigned short* qt = (const unsigned short*)(lds_raw + (c & 1) * 16384);
        #pragma unroll
        for (int ms = 0; ms < 8; ++ms) {
            const int row = ms * 16 + col;
            const bf16x8 b0 = *(const bf16x8*)(qt + row * 64 + ((quad ^ (col & 7)) * 8));
            const bf16x8 b1 = *(const bf16x8*)(qt + row * 64 + (((4 + quad) ^ (col & 7)) * 8));
            float cpv = 0.f;
            #pragma unroll
            for (int s = 0; s < 4; ++s) {
                f32x4 acc = {0.f, 0.f, 0.f, 0.f};
                acc = MFMA16(a0[s], b0, acc);
                acc = MFMA16(a1[s], b1, acc);
                #pragma unroll
                for (int r = 0; r < 4; ++r) {
                    const float e = __builtin_amdgcn_exp2f(acc[r]);
                    rs[s][r] += e;
                    cpv += e;
                }
            }
            cp[c * 8 + ms] += cpv;
        }
        __syncthreads();
    }

    // row direction: reduce over the 16 cols, atomic-add into rowsum[n]
    #pragma unroll
    for (int s = 0; s < 4; ++s)
        #pragma unroll
        for (int r = 0; r < 4; ++r) {
            #pragma unroll
            for (int off = 1; off < 16; off <<= 1)
                rs[s][r] += __shfl_xor(rs[s][r], off, 64);
        }
    if (col == 0) {
        #pragma unroll
        for (int s = 0; s < 4; ++s)
            #pragma unroll
            for (int r = 0; r < 4; ++r)
                atomicAdd(&rsb[n_base + s * 16 + quad * 4 + r], rs[s][r]);
    }

    // col direction (symmetry): reduce over quads, atomic-add into rowsum[m]
    if (ti != tj) {
        #pragma unroll
        for (int g = 0; g < 16; ++g) {
            float v = cp[g];
            v += __shfl_xor(v, 16, 64);
            v += __shfl_xor(v, 32, 64);
            if (quad == 0) atomicAdd(&rsb[m_base + g * 16 + col], v);
        }
    }
}

// ---------------------------------------------------------------------------
// K2bc: winv = 1/rowsum (LDS-local); wbf = bf16(winv); xv *= winv in place.
//       Also zeros the bn accumulator (block 0) for k4's atomics.
// ---------------------------------------------------------------------------
__global__ __launch_bounds__(256) void k2bc(
    const float* __restrict__ rowsum, unsigned short* __restrict__ xv_bf,
    unsigned short* __restrict__ wbf, float* __restrict__ bn)
{
    __shared__ float wl[64];
    const int tid = threadIdx.x;
    const int b = blockIdx.x & 7;
    const int n0 = (blockIdx.x >> 3) * 64;
    if (blockIdx.x == 0 && tid < 128) bn[tid] = 0.f;
    if (tid < 64) {
        const float w = 1.0f / rowsum[b * N_ + n0 + tid];
        wl[tid] = w;
        wbf[b * N_ + n0 + tid] = f2bf(w);
    }
    __syncthreads();
    #pragma unroll
    for (int it = 0; it < 4; ++it) {
        const int idx4 = it * 256 + tid;               // [0, 1024)
        const int o = idx4 >> 4, n4 = (idx4 & 15) * 4;
        unsigned short* p = xv_bf + (size_t)(b * C2_ + o) * N_ + n0 + n4;
        us4 v = *(us4*)p;
        v.a = f2bf(bf2f(v.a) * wl[n4 + 0]);
        v.b = f2bf(bf2f(v.b) * wl[n4 + 1]);
        v.c = f2bf(bf2f(v.c) * wl[n4 + 2]);
        v.d = f2bf(bf2f(v.d) * wl[n4 + 3]);
        *(us4*)p = v;
    }
}

// ---------------------------------------------------------------------------
// K3: block owns 128 m-cols and a THIRD of n (split-K, grid 768, 3 blk/CU).
//     Waves: (m-half mh, n-half nh2).  Per 64-n chunk: stage qk slab + xv tile
//     (dbuf DMA); each wave computes E for its 32 n x 64 m; S' = exp2(E)
//     (row-normalizer pre-folded into xv); LDS round-trip; PV MFMA + colsum
//     MFMA (A-rows = wbf).  Epilogue: cross n-half combine in LDS; write
//     partial Y + partial colsum; k4 combines the 3 splits.
// ---------------------------------------------------------------------------
__global__ __launch_bounds__(256, 3) void k3_pv(
    const unsigned short* __restrict__ qk_t, const unsigned short* __restrict__ xv_bf,
    const unsigned short* __restrict__ wbf,
    float* __restrict__ yp0, float* __restrict__ yp1, float* __restrict__ yp2,
    float* __restrict__ cspart)
{
    // 0..16K: qk dbuf | 16K..32K: xv dbuf | 32K..52K: S tiles (4 waves x [4g][16][40])
    __shared__ __align__(16) unsigned char lds_raw[32768 + 4 * 5120];
    const int tid = threadIdx.x;
    const int wave = tid >> 6, lane = tid & 63;
    const int quad = lane >> 4, col = lane & 15;
    const int nh2 = wave & 1, mh = wave >> 1;
    const int b = blockIdx.x & 7;
    const int m_blk = ((blockIdx.x >> 3) & 31) * 128;
    const int sk = blockIdx.x >> 8;                  // 0..2 (split-K index)
    const int n_start = (sk == 0) ? 0 : 1408 + (sk - 1) * 1344;
    const int n_chunks = (sk == 0) ? 22 : 21;
    const int m_wave = m_blk + mh * 64;
    const unsigned short* qb = qk_t + (size_t)b * N_ * C2_;
    const unsigned short* vb = xv_bf + (size_t)b * C2_ * N_;
    const unsigned short* wb = wbf + b * N_;
    float* yp = (sk == 0) ? yp0 : (sk == 1) ? yp1 : yp2;

    // persistent B-operands for E: this wave's 64 m-cols (4 groups of 16)
    bf16x8 kb0[4], kb1[4];
    #pragma unroll
    for (int g = 0; g < 4; ++g) {
        const unsigned short* p = qb + (size_t)(m_wave + g * 16 + col) * C2_ + quad * 8;
        kb0[g] = *(const bf16x8*)p;
        kb1[g] = *(const bf16x8*)(p + 32);
    }

    unsigned short* stS = (unsigned short*)(lds_raw + 32768 + wave * 5120); // [g][col][40]

    auto stage = [&](int n0, int p) {
        unsigned char* qbase = lds_raw + p * 8192;
        unsigned char* vbase = lds_raw + 16384 + p * 8192;
        #pragma unroll
        for (int r = 0; r < 2; ++r) {
            const int idx = r * 256 + tid;
            const int row = idx >> 3, seg = idx & 7;
            const int ss = seg ^ (row & 7);
            gl_lds16(qb + (size_t)(n0 + row) * C2_ + (size_t)ss * 8, qbase + idx * 16);
            gl_lds16(vb + (size_t)row * N_ + n0 + ss * 8, vbase + idx * 16);
        }
    };

    f32x4 accY[4][4];
    #pragma unroll
    for (int g = 0; g < 4; ++g)
        #pragma unroll
        for (int os = 0; os < 4; ++os) accY[g][os] = (f32x4){0.f, 0.f, 0.f, 0.f};
    f32x4 csacc[4];
    #pragma unroll
    for (int g = 0; g < 4; ++g) csacc[g] = (f32x4){0.f, 0.f, 0.f, 0.f};

    stage(n_start, 0);
    __syncthreads();

    for (int c = 0; c < n_chunks; ++c) {
        const int n0 = n_start + c * 64;
        const int p = c & 1;
        if (c + 1 < n_chunks) stage(n0 + 64, 1 - p);

        const unsigned short* qt = (const unsigned short*)(lds_raw + p * 8192);
        const unsigned short* vt = (const unsigned short*)(lds_raw + 16384 + p * 8192);

        // colsum weight fragment for this wave's 32-n slice (tiny L1 load)
        const bf16x8 wfrag = *(const bf16x8*)(wb + n0 + nh2 * 32 + quad * 8);

        // E phase over this wave's 32 n-rows; S' = exp2(E') straight to LDS
        #pragma unroll
        for (int ns = 0; ns < 2; ++ns) {
            const int row = nh2 * 32 + ns * 16 + col;
            const bf16x8 qa0 = *(const bf16x8*)(qt + row * 64 + ((quad ^ (col & 7)) * 8));
            const bf16x8 qa1 = *(const bf16x8*)(qt + row * 64 + (((4 + quad) ^ (col & 7)) * 8));
            #pragma unroll
            for (int g = 0; g < 4; ++g) {
                f32x4 acc = {0.f, 0.f, 0.f, 0.f};
                acc = MFMA16(qa0, kb0[g], acc);
                acc = MFMA16(qa1, kb1[g], acc);
                union { unsigned short us[4]; uint2 u2; } pk;
                #pragma unroll
                for (int r = 0; r < 4; ++r)
                    pk.us[r] = f2bf(__builtin_amdgcn_exp2f(acc[r]));
                *(uint2*)&stS[(g * 16 + col) * 40 + ns * 16 + quad * 4] = pk.u2;
            }
        }

        // same-wave round-trip: S' as B-operand (K = this wave's 32 n)
        bf16x8 sB[4];
        #pragma unroll
        for (int g = 0; g < 4; ++g)
            sB[g] = *(const bf16x8*)&stS[(g * 16 + col) * 40 + quad * 8];

        // colsum via MFMA: A rows all = w  ->  D rows all = colsum
        #pragma unroll
        for (int g = 0; g < 4; ++g)
            csacc[g] = MFMA16(wfrag, sB[g], csacc[g]);

        // PV: A = xv rows (o), k = this wave's 32 n
        #pragma unroll
        for (int os = 0; os < 4; ++os) {
            const bf16x8 va = *(const bf16x8*)(vt + (os * 16 + col) * 64 +
                                               (((nh2 * 4 + quad) ^ (col & 7)) * 8));
            #pragma unroll
            for (int g = 0; g < 4; ++g)
                accY[g][os] = MFMA16(va, sB[g], accY[g][os]);
        }
        __syncthreads();
    }

    // epilogue: combine the two n-halves (waves nh2=1 -> LDS; nh2=0 adds+writes)
    float* cmb = (float*)lds_raw;              // 32 KB: [mh][g*4+os][r][lane]
    float* csc = (float*)(lds_raw + 32768);    // 2 KB:  [mh][g][lane]
    if (nh2 == 1) {
        #pragma unroll
        for (int g = 0; g < 4; ++g) {
            #pragma unroll
            for (int os = 0; os < 4; ++os)
                #pragma unroll
                for (int r = 0; r < 4; ++r)
                    cmb[((mh * 16 + g * 4 + os) * 4 + r) * 64 + lane] = accY[g][os][r];
            csc[(mh * 4 + g) * 64 + lane] = csacc[g][0];
        }
    }
    __syncthreads();
    if (nh2 == 0) {
        #pragma unroll
        for (int g = 0; g < 4; ++g) {
            const float cs = csacc[g][0] + csc[(mh * 4 + g) * 64 + lane];
            if (lane < 16)
                cspart[((size_t)sk * 8 + b) * N_ + m_wave + g * 16 + lane] = cs;
            #pragma unroll
            for (int os = 0; os < 4; ++os)
                #pragma unroll
                for (int r = 0; r < 4; ++r) {
                    const float v = accY[g][os][r] +
                        cmb[((mh * 16 + g * 4 + os) * 4 + r) * 64 + lane];
                    yp[(size_t)(b * C2_ + os * 16 + quad * 4 + r) * N_ + m_wave + g * 16 + col] = v;
                }
        }
    }
}

// ---------------------------------------------------------------------------
// K4: fused partial-combine + w_t GEMM (MFMA) + BN stats via atomicAdd(bn).
//     Per (b, 64-n tile): cinv = 1/(eps+sum cspart); d = xc - (y0+y1+y2)*cinv
//     staged TRANSPOSED to LDS bf16 d_t[n][72]; w_t staged bf16 [o][72].
//     Wave = o-tile; K = 64 -> kt in [0,2).  t = acc + b_t -> t_buf.
//     NOTE: reads y1 region == writes t_buf region; all reads complete
//     before the post-staging barrier, writes only after (same tile only).
// ---------------------------------------------------------------------------
__global__ __launch_bounds__(256) void k4_t(
    const float* __restrict__ xc, const float* __restrict__ y0,
    const float* __restrict__ y1, const float* __restrict__ y2,
    const float* __restrict__ cspart, const float* __restrict__ w_t,
    const float* __restrict__ b_t, float* __restrict__ t_buf,
    float* __restrict__ bn)
{
    __shared__ __align__(16) unsigned short wlds[64 * 72];
    __shared__ __align__(16) unsigned short d_t[64 * 72];
    __shared__ float cinv[64];
    const int tid = threadIdx.x;
    const int wave = tid >> 6, lane = tid & 63;
    const int quad = lane >> 4, col = lane & 15;
    const int b = blockIdx.y;
    const int n0 = blockIdx.x * 64;
    const size_t base = (size_t)b * C2_ * N_;

    // phase 0: w_t -> bf16 LDS; per-n colsum inverse
    #pragma unroll
    for (int it = 0; it < 4; ++it) {
        const int idx4 = it * 256 + tid;               // [0, 1024)
        const int o = idx4 >> 4, i4 = (idx4 & 15) * 4;
        const float4 v = *(const float4*)(w_t + o * 64 + i4);
        us4 pk;
        pk.a = f2bf(v.x); pk.b = f2bf(v.y); pk.c = f2bf(v.z); pk.d = f2bf(v.w);
        *(us4*)&wlds[o * 72 + i4] = pk;
    }
    if (tid < 64) {
        const int n = n0 + tid;
        const float cs = cspart[(size_t)b * N_ + n] + cspart[(size_t)(8 + b) * N_ + n]
                       + cspart[(size_t)(16 + b) * N_ + n];
        cinv[tid] = 1.0f / (1e-9f + cs);
    }
    __syncthreads();

    // phase 1: d = xc - (y0+y1+y2)*cinv, transposed bf16 -> d_t[n][i]
    #pragma unroll
    for (int it = 0; it < 4; ++it) {
        const int idx4 = it * 256 + tid;               // [0, 1024)
        const int i = idx4 >> 4, n4 = (idx4 & 15) * 4;
        const size_t g = base + (size_t)i * N_ + n0 + n4;
        const float4 c4 = *(const float4*)(xc + g);
        const float4 a0 = *(const float4*)(y0 + g);
        const float4 a1 = *(const float4*)(y1 + g);
        const float4 a2 = *(const float4*)(y2 + g);
        d_t[(n4 + 0) * 72 + i] = f2bf(c4.x - (a0.x + a1.x + a2.x) * cinv[n4 + 0]);
        d_t[(n4 + 1) * 72 + i] = f2bf(c4.y - (a0.y + a1.y + a2.y) * cinv[n4 + 1]);
        d_t[(n4 + 2) * 72 + i] = f2bf(c4.z - (a0.z + a1.z + a2.z) * cinv[n4 + 2]);
        d_t[(n4 + 3) * 72 + i] = f2bf(c4.w - (a0.w + a1.w + a2.w) * cinv[n4 + 3]);
    }
    __syncthreads();

    const int ow = wave * 16;
    bf16x8 afr[2];
    #pragma unroll
    for (int kt = 0; kt < 2; ++kt)
        afr[kt] = *(const bf16x8*)&wlds[(ow + col) * 72 + kt * 32 + quad * 8];
    const float4 bt4 = *(const float4*)(b_t + ow + quad * 4);
    const float* btp = (const float*)&bt4;

    float s[4] = {0.f, 0.f, 0.f, 0.f}, q2[4] = {0.f, 0.f, 0.f, 0.f};
    #pragma unroll
    for (int ns = 0; ns < 4; ++ns) {
        f32x4 acc = {0.f, 0.f, 0.f, 0.f};
        #pragma unroll
        for (int kt = 0; kt < 2; ++kt) {
            const bf16x8 bfr = *(const bf16x8*)&d_t[(ns * 16 + col) * 72 + kt * 32 + quad * 8];
            acc = MFMA16(afr[kt], bfr, acc);
        }
        #pragma unroll
        for (int r = 0; r < 4; ++r) {
            const float t = acc[r] + btp[r];
            t_buf[base + (size_t)(ow + quad * 4 + r) * N_ + n0 + ns * 16 + col] = t;
            s[r] += t;
            q2[r] += t * t;
        }
    }
    #pragma unroll
    for (int r = 0; r < 4; ++r) {
        #pragma unroll
        for (int off = 1; off < 16; off <<= 1) {
            s[r]  += __shfl_xor(s[r],  off, 64);
            q2[r] += __shfl_xor(q2[r], off, 64);
        }
    }
    if (col == 0) {
        #pragma unroll
        for (int r = 0; r < 4; ++r) {
            atomicAdd(&bn[ow + quad * 4 + r],      s[r]);
            atomicAdd(&bn[64 + ow + quad * 4 + r], q2[r]);
        }
    }
}

// ---------------------------------------------------------------------------
// K6: out = xc + relu(gamma * (t - mean) * rsqrt(var + eps) + beta)
// ---------------------------------------------------------------------------
__global__ __launch_bounds__(256) void k6_out(
    const float* __restrict__ xc, const float* __restrict__ t_buf,
    const float* __restrict__ bn, const float* __restrict__ gamma,
    const float* __restrict__ beta, float* __restrict__ out)
{
    const int idx = blockIdx.x * 256 + threadIdx.x;
    const int o = (idx >> 10) & 63;
    const float invC = 1.0f / (float)(B_ * N_);
    const float mean = bn[o] * invC;
    const float var  = bn[64 + o] * invC - mean * mean;
    const float sc = gamma[o] * rsqrtf(var + 1e-5f);
    const float sh = beta[o] - mean * sc;
    const float4 t4 = ((const float4*)t_buf)[idx];
    const float4 c4 = ((const float4*)xc)[idx];
    float4 r;
    r.x = c4.x + fmaxf(0.f, sc * t4.x + sh);
    r.y = c4.y + fmaxf(0.f, sc * t4.y + sh);
    r.z = c4.z + fmaxf(0.f, sc * t4.z + sh);
    r.w = c4.w + fmaxf(0.f, sc * t4.w + sh);
    ((float4*)out)[idx] = r;
}

extern "C" void kernel_launch(void* const* d_in, const int* in_sizes, int n_in,
                              void* d_out, int out_size, void* d_ws, size_t ws_size,
                              hipStream_t stream) {
    const float* x     = (const float*)d_in[0];
    const float* w_qk  = (const float*)d_in[1];
    const float* w_v   = (const float*)d_in[2];
    const float* b_v   = (const float*)d_in[3];
    const float* w_x   = (const float*)d_in[4];
    const float* w_t   = (const float*)d_in[5];
    const float* b_t   = (const float*)d_in[6];
    const float* gamma = (const float*)d_in[7];
    const float* beta  = (const float*)d_in[8];
    float* out = (float*)d_out;

    char* ws = (char*)d_ws;
    unsigned short* qk_t  = (unsigned short*)ws;                      // 4 MB
    unsigned short* xv_bf = (unsigned short*)(ws + (4  << 20));       // 4 MB
    float* xc      = (float*)(ws + (8  << 20));                       // 8 MB
    float* yp0     = (float*)(ws + (16 << 20));                       // 8 MB
    float* tb_yp1  = (float*)(ws + (24 << 20));                       // 8 MB (ypart1, then t_buf)
    float* rowsum  = (float*)(ws + (32 << 20));                       // 128 KB (k1 zero, k2 atomics)
    float* cspart  = (float*)(ws + (32 << 20));                       // 384 KB (k3 -> k4; reuses rowsum)
    unsigned short* wbf = (unsigned short*)(ws + (33 << 20));         // 64 KB
    float* bn      = (float*)(ws + (33 << 20) + (64 << 10));          // 512 B
    float* yp2     = out;                                             // 8 MB scratch until k4

    hipLaunchKernelGGL(k1_proj,     dim3(64, 8),  256, 0, stream,
                       x, w_qk, w_v, b_v, w_x, qk_t, xv_bf, xc, rowsum);
    hipLaunchKernelGGL(k2_rowstats, dim3(1088),   256, 0, stream, qk_t, rowsum);
    hipLaunchKernelGGL(k2bc,        dim3(512),    256, 0, stream, rowsum, xv_bf, wbf, bn);
    hipLaunchKernelGGL(k3_pv,       dim3(768),    256, 0, stream,
                       qk_t, xv_bf, wbf, yp0, tb_yp1, yp2, cspart);
    hipLaunchKernelGGL(k4_t,        dim3(64, 8),  256, 0, stream,
                       xc, yp0, tb_yp1, yp2, cspart, w_t, b_t, tb_yp1, bn);
    hipLaunchKernelGGL(k6_out,      dim3(2048),   256, 0, stream, xc, tb_yp1, bn, gamma, beta, out);
}

// Round 11
// 172.003 us; speedup vs baseline: 1.3427x; 1.3427x over previous
//
#include <hip/hip_runtime.h>

#define B_   8
#define C_   128
#define N_   4096
#define C2_  64

typedef __bf16 bf16x8 __attribute__((ext_vector_type(8)));
typedef float  f32x4  __attribute__((ext_vector_type(4)));

#define MFMA16(a, b, c) __builtin_amdgcn_mfma_f32_16x16x32_bf16((a), (b), (c), 0, 0, 0)

// sqrt(log2(e)): fold into q/k so softmax uses exp2 directly (E' = E * log2e)
#define QK_SCALE 1.2011224087864498f

static __device__ __forceinline__ unsigned short f2bf(float f) {
    union { __bf16 b; unsigned short u; } cv;
    cv.b = (__bf16)f;
    return cv.u;
}
static __device__ __forceinline__ float bf2f(unsigned short u) {
    union { unsigned int u; float f; } cv;
    cv.u = ((unsigned int)u) << 16;
    return cv.f;
}

struct us4 { unsigned short a, b, c, d; };

// async global->LDS, 16 B per lane.  LDS dest must be linear in lane order.
static __device__ __forceinline__ void gl_lds16(const unsigned short* g, void* l) {
    __builtin_amdgcn_global_load_lds(
        (const __attribute__((address_space(1))) unsigned int*)g,
        (__attribute__((address_space(3))) unsigned int*)l,
        16, 0, 0);
}

// ---------------------------------------------------------------------------
// K1: fused projection GEMM.  D[192 o][64 n] = W(3x64 stacked)[o][c] * x[c][n]
//     per (b, 64-n tile).  Weights -> LDS bf16 [192][136]; x tile transposed
//     -> LDS bf16 x_t[64 n][136 c].  Epilogue: ot 0-3 -> qk_t (us4, *QK_SCALE);
//     ot 4-7 -> xv_bf (+b_v); ot 8-11 -> xc (f32).
// ---------------------------------------------------------------------------
__global__ __launch_bounds__(256) void k1_proj(
    const float* __restrict__ x, const float* __restrict__ w_qk,
    const float* __restrict__ w_v, const float* __restrict__ b_v,
    const float* __restrict__ w_x,
    unsigned short* __restrict__ qk_t, unsigned short* __restrict__ xv_bf,
    float* __restrict__ xc)
{
    __shared__ __align__(16) unsigned short w_lds[192 * 136];
    __shared__ __align__(16) unsigned short x_t[64 * 136];
    const int tid = threadIdx.x;
    const int wave = tid >> 6, lane = tid & 63;
    const int quad = lane >> 4, col = lane & 15;
    const int b = blockIdx.y;
    const int n0 = blockIdx.x * 64;

    const float* wsrc[3] = {w_qk, w_v, w_x};
    #pragma unroll
    for (int mat = 0; mat < 3; ++mat) {
        const float* wm = wsrc[mat];
        #pragma unroll
        for (int it = 0; it < 8; ++it) {
            const int idx = it * 256 + tid;            // [0, 2048)
            const int o = idx >> 5, c = (idx & 31) * 4;
            const float4 v = *(const float4*)(wm + o * C_ + c);
            us4 pk;
            pk.a = f2bf(v.x); pk.b = f2bf(v.y); pk.c = f2bf(v.z); pk.d = f2bf(v.w);
            *(us4*)&w_lds[(mat * 64 + o) * 136 + c] = pk;
        }
    }
    const float* xb = x + (size_t)b * C_ * N_ + n0;
    #pragma unroll
    for (int it = 0; it < 8; ++it) {
        const int idx = it * 256 + tid;                // [0, 2048)
        const int c = idx >> 4, n = (idx & 15) * 4;
        const float4 v = *(const float4*)(xb + (size_t)c * N_ + n);
        x_t[(n + 0) * 136 + c] = f2bf(v.x);
        x_t[(n + 1) * 136 + c] = f2bf(v.y);
        x_t[(n + 2) * 136 + c] = f2bf(v.z);
        x_t[(n + 3) * 136 + c] = f2bf(v.w);
    }
    __syncthreads();

    const int nw = wave * 16;
    bf16x8 bfr[4];
    #pragma unroll
    for (int kt = 0; kt < 4; ++kt)
        bfr[kt] = *(const bf16x8*)&x_t[(nw + col) * 136 + kt * 32 + quad * 8];

    const int n_g = n0 + nw + col;

    #pragma unroll
    for (int ot = 0; ot < 12; ++ot) {
        f32x4 acc = {0.f, 0.f, 0.f, 0.f};
        #pragma unroll
        for (int kt = 0; kt < 4; ++kt) {
            const bf16x8 afr = *(const bf16x8*)&w_lds[(ot * 16 + col) * 136 + kt * 32 + quad * 8];
            acc = MFMA16(afr, bfr[kt], acc);
        }
        if (ot < 4) {
            us4 pk;
            pk.a = f2bf(acc[0] * QK_SCALE); pk.b = f2bf(acc[1] * QK_SCALE);
            pk.c = f2bf(acc[2] * QK_SCALE); pk.d = f2bf(acc[3] * QK_SCALE);
            *(us4*)&qk_t[(size_t)(b * N_ + n_g) * C2_ + ot * 16 + quad * 4] = pk;
        } else if (ot < 8) {
            const float4 bv4 = *(const float4*)(b_v + (ot - 4) * 16 + quad * 4);
            const float* bvp = (const float*)&bv4;
            #pragma unroll
            for (int r = 0; r < 4; ++r)
                xv_bf[(size_t)(b * C2_ + (ot - 4) * 16 + quad * 4 + r) * N_ + n_g]
                    = f2bf(acc[r] + bvp[r]);
        } else {
            #pragma unroll
            for (int r = 0; r < 4; ++r)
                xc[(size_t)(b * C2_ + (ot - 8) * 16 + quad * 4 + r) * N_ + n_g] = acc[r];
        }
    }
}

// ---------------------------------------------------------------------------
// K2: partial row softmax sums.  Grid 1024: b=id&7, nblk=(id>>3)&15, mq=id>>7.
//     Wave owns 64 n-rows (4 A-frag sets); block owns 256 rows x 512 m as
//     4 chunks of 128 m (32 KB dbuf).  Writes part_rs[mq][b][n].  4 blocks/CU.
// ---------------------------------------------------------------------------
__global__ __launch_bounds__(256) void k2_rowstats(
    const unsigned short* __restrict__ qk_t, float* __restrict__ part_rs)
{
    __shared__ __align__(16) unsigned char lds_raw[2 * 16384];
    const int tid = threadIdx.x;
    const int wave = tid >> 6, lane = tid & 63;
    const int quad = lane >> 4, col = lane & 15;
    const int b = blockIdx.x & 7;
    const int nblk = (blockIdx.x >> 3) & 15;
    const int mq = blockIdx.x >> 7;                   // 0..7
    const int n_base = nblk * 256 + wave * 64;
    const int m_start = mq * 512;
    const unsigned short* qb = qk_t + (size_t)b * N_ * C2_;

    // four persistent A-frag sets: rows n_base + s*16 + col
    bf16x8 a0[4], a1[4];
    #pragma unroll
    for (int s = 0; s < 4; ++s) {
        const unsigned short* p = qb + (size_t)(n_base + s * 16 + col) * C2_ + quad * 8;
        a0[s] = *(const bf16x8*)p;
        a1[s] = *(const bf16x8*)(p + 32);
    }

    // stage 128 m-rows (16 KB) into buffer p
    auto stage = [&](int m0, int p) {
        unsigned char* base = lds_raw + p * 16384;
        #pragma unroll
        for (int r = 0; r < 4; ++r) {
            const int idx = r * 256 + tid;             // [0, 1024)
            const int row = idx >> 3, seg = idx & 7;
            gl_lds16(qb + (size_t)(m0 + row) * C2_ + (size_t)(seg ^ (row & 7)) * 8,
                     base + idx * 16);
        }
    };

    float run_s[4][4];
    #pragma unroll
    for (int s = 0; s < 4; ++s)
        #pragma unroll
        for (int r = 0; r < 4; ++r) run_s[s][r] = 0.f;

    stage(m_start, 0);
    __syncthreads();

    for (int c = 0; c < 4; ++c) {
        const int p = c & 1;
        if (c + 1 < 4) stage(m_start + (c + 1) * 128, 1 - p);
        const unsigned short* qt = (const unsigned short*)(lds_raw + p * 16384);
        #pragma unroll
        for (int ms = 0; ms < 8; ++ms) {
            const int row = ms * 16 + col;
            const bf16x8 b0 = *(const bf16x8*)(qt + row * 64 + ((quad ^ (col & 7)) * 8));
            const bf16x8 b1 = *(const bf16x8*)(qt + row * 64 + (((4 + quad) ^ (col & 7)) * 8));
            #pragma unroll
            for (int s = 0; s < 4; ++s) {
                f32x4 acc = {0.f, 0.f, 0.f, 0.f};
                acc = MFMA16(a0[s], b0, acc);
                acc = MFMA16(a1[s], b1, acc);
                #pragma unroll
                for (int r = 0; r < 4; ++r)
                    run_s[s][r] += __builtin_amdgcn_exp2f(acc[r]);
            }
        }
        __syncthreads();
    }

    #pragma unroll
    for (int s = 0; s < 4; ++s)
        #pragma unroll
        for (int r = 0; r < 4; ++r) {
            #pragma unroll
            for (int off = 1; off < 16; off <<= 1)
                run_s[s][r] += __shfl_xor(run_s[s][r], off, 64);
        }
    if (col == 0) {
        #pragma unroll
        for (int s = 0; s < 4; ++s)
            #pragma unroll
            for (int r = 0; r < 4; ++r)
                part_rs[((size_t)(mq * 8 + b) << 12) + n_base + s * 16 + quad * 4 + r]
                    = run_s[s][r];
    }
}

// ---------------------------------------------------------------------------
// K2bc: fused rowsum-combine + xv scale.  Grid 512: b=id&7, nt=id>>3.
//       winv = 1/rowsum (LDS-local); wbf = bf16(winv); xv *= winv in place.
// ---------------------------------------------------------------------------
__global__ __launch_bounds__(256) void k2bc(
    const float* __restrict__ part_rs, unsigned short* __restrict__ xv_bf,
    unsigned short* __restrict__ wbf)
{
    __shared__ float wl[64];
    const int tid = threadIdx.x;
    const int b = blockIdx.x & 7;
    const int n0 = (blockIdx.x >> 3) * 64;
    if (tid < 64) {
        float s = 0.f;
        #pragma unroll
        for (int q = 0; q < 8; ++q)
            s += part_rs[((size_t)(q * 8 + b) << 12) + n0 + tid];
        const float w = 1.0f / s;
        wl[tid] = w;
        wbf[b * N_ + n0 + tid] = f2bf(w);
    }
    __syncthreads();
    #pragma unroll
    for (int it = 0; it < 4; ++it) {
        const int idx4 = it * 256 + tid;               // [0, 1024)
        const int o = idx4 >> 4, n4 = (idx4 & 15) * 4;
        unsigned short* p = xv_bf + (size_t)(b * C2_ + o) * N_ + n0 + n4;
        us4 v = *(us4*)p;
        v.a = f2bf(bf2f(v.a) * wl[n4 + 0]);
        v.b = f2bf(bf2f(v.b) * wl[n4 + 1]);
        v.c = f2bf(bf2f(v.c) * wl[n4 + 2]);
        v.d = f2bf(bf2f(v.d) * wl[n4 + 3]);
        *(us4*)p = v;
    }
}

// ---------------------------------------------------------------------------
// K3: block owns 128 m-cols and a THIRD of n (split-K, grid 768, 3 blk/CU).
//     Waves: (m-half mh, n-half nh2).  Per 64-n chunk: stage qk slab + xv tile
//     (dbuf DMA); each wave computes E for its 32 n x 64 m; S' = exp2(E)
//     (row-normalizer pre-folded into xv); LDS round-trip; PV MFMA + colsum
//     MFMA (A-rows = wbf).  Epilogue: cross n-half combine in LDS; write
//     partial Y + partial colsum; k4 combines the 3 splits.
// ---------------------------------------------------------------------------
__global__ __launch_bounds__(256, 3) void k3_pv(
    const unsigned short* __restrict__ qk_t, const unsigned short* __restrict__ xv_bf,
    const unsigned short* __restrict__ wbf,
    float* __restrict__ yp0, float* __restrict__ yp1, float* __restrict__ yp2,
    float* __restrict__ cspart)
{
    // 0..16K: qk dbuf | 16K..32K: xv dbuf | 32K..52K: S tiles (4 waves x [4g][16][40])
    __shared__ __align__(16) unsigned char lds_raw[32768 + 4 * 5120];
    const int tid = threadIdx.x;
    const int wave = tid >> 6, lane = tid & 63;
    const int quad = lane >> 4, col = lane & 15;
    const int nh2 = wave & 1, mh = wave >> 1;
    const int b = blockIdx.x & 7;
    const int m_blk = ((blockIdx.x >> 3) & 31) * 128;
    const int sk = blockIdx.x >> 8;                  // 0..2 (split-K index)
    const int n_start = (sk == 0) ? 0 : 1408 + (sk - 1) * 1344;
    const int n_chunks = (sk == 0) ? 22 : 21;
    const int m_wave = m_blk + mh * 64;
    const unsigned short* qb = qk_t + (size_t)b * N_ * C2_;
    const unsigned short* vb = xv_bf + (size_t)b * C2_ * N_;
    const unsigned short* wb = wbf + b * N_;
    float* yp = (sk == 0) ? yp0 : (sk == 1) ? yp1 : yp2;

    // persistent B-operands for E: this wave's 64 m-cols (4 groups of 16)
    bf16x8 kb0[4], kb1[4];
    #pragma unroll
    for (int g = 0; g < 4; ++g) {
        const unsigned short* p = qb + (size_t)(m_wave + g * 16 + col) * C2_ + quad * 8;
        kb0[g] = *(const bf16x8*)p;
        kb1[g] = *(const bf16x8*)(p + 32);
    }

    unsigned short* stS = (unsigned short*)(lds_raw + 32768 + wave * 5120); // [g][col][40]

    auto stage = [&](int n0, int p) {
        unsigned char* qbase = lds_raw + p * 8192;
        unsigned char* vbase = lds_raw + 16384 + p * 8192;
        #pragma unroll
        for (int r = 0; r < 2; ++r) {
            const int idx = r * 256 + tid;
            const int row = idx >> 3, seg = idx & 7;
            const int ss = seg ^ (row & 7);
            gl_lds16(qb + (size_t)(n0 + row) * C2_ + (size_t)ss * 8, qbase + idx * 16);
            gl_lds16(vb + (size_t)row * N_ + n0 + ss * 8, vbase + idx * 16);
        }
    };

    f32x4 accY[4][4];
    #pragma unroll
    for (int g = 0; g < 4; ++g)
        #pragma unroll
        for (int os = 0; os < 4; ++os) accY[g][os] = (f32x4){0.f, 0.f, 0.f, 0.f};
    f32x4 csacc[4];
    #pragma unroll
    for (int g = 0; g < 4; ++g) csacc[g] = (f32x4){0.f, 0.f, 0.f, 0.f};

    stage(n_start, 0);
    __syncthreads();

    for (int c = 0; c < n_chunks; ++c) {
        const int n0 = n_start + c * 64;
        const int p = c & 1;
        if (c + 1 < n_chunks) stage(n0 + 64, 1 - p);

        const unsigned short* qt = (const unsigned short*)(lds_raw + p * 8192);
        const unsigned short* vt = (const unsigned short*)(lds_raw + 16384 + p * 8192);

        // colsum weight fragment for this wave's 32-n slice (tiny L1 load)
        const bf16x8 wfrag = *(const bf16x8*)(wb + n0 + nh2 * 32 + quad * 8);

        // E phase over this wave's 32 n-rows; S' = exp2(E') straight to LDS
        #pragma unroll
        for (int ns = 0; ns < 2; ++ns) {
            const int row = nh2 * 32 + ns * 16 + col;
            const bf16x8 qa0 = *(const bf16x8*)(qt + row * 64 + ((quad ^ (col & 7)) * 8));
            const bf16x8 qa1 = *(const bf16x8*)(qt + row * 64 + (((4 + quad) ^ (col & 7)) * 8));
            #pragma unroll
            for (int g = 0; g < 4; ++g) {
                f32x4 acc = {0.f, 0.f, 0.f, 0.f};
                acc = MFMA16(qa0, kb0[g], acc);
                acc = MFMA16(qa1, kb1[g], acc);
                union { unsigned short us[4]; uint2 u2; } pk;
                #pragma unroll
                for (int r = 0; r < 4; ++r)
                    pk.us[r] = f2bf(__builtin_amdgcn_exp2f(acc[r]));
                *(uint2*)&stS[(g * 16 + col) * 40 + ns * 16 + quad * 4] = pk.u2;
            }
        }

        // same-wave round-trip: S' as B-operand (K = this wave's 32 n)
        bf16x8 sB[4];
        #pragma unroll
        for (int g = 0; g < 4; ++g)
            sB[g] = *(const bf16x8*)&stS[(g * 16 + col) * 40 + quad * 8];

        // colsum via MFMA: A rows all = w  ->  D rows all = colsum
        #pragma unroll
        for (int g = 0; g < 4; ++g)
            csacc[g] = MFMA16(wfrag, sB[g], csacc[g]);

        // PV: A = xv rows (o), k = this wave's 32 n
        #pragma unroll
        for (int os = 0; os < 4; ++os) {
            const bf16x8 va = *(const bf16x8*)(vt + (os * 16 + col) * 64 +
                                               (((nh2 * 4 + quad) ^ (col & 7)) * 8));
            #pragma unroll
            for (int g = 0; g < 4; ++g)
                accY[g][os] = MFMA16(va, sB[g], accY[g][os]);
        }
        __syncthreads();
    }

    // epilogue: combine the two n-halves (waves nh2=1 -> LDS; nh2=0 adds+writes)
    float* cmb = (float*)lds_raw;              // 32 KB: [mh][g*4+os][r][lane]
    float* csc = (float*)(lds_raw + 32768);    // 2 KB:  [mh][g][lane]
    if (nh2 == 1) {
        #pragma unroll
        for (int g = 0; g < 4; ++g) {
            #pragma unroll
            for (int os = 0; os < 4; ++os)
                #pragma unroll
                for (int r = 0; r < 4; ++r)
                    cmb[((mh * 16 + g * 4 + os) * 4 + r) * 64 + lane] = accY[g][os][r];
            csc[(mh * 4 + g) * 64 + lane] = csacc[g][0];
        }
    }
    __syncthreads();
    if (nh2 == 0) {
        #pragma unroll
        for (int g = 0; g < 4; ++g) {
            const float cs = csacc[g][0] + csc[(mh * 4 + g) * 64 + lane];
            if (lane < 16)
                cspart[((size_t)sk * 8 + b) * N_ + m_wave + g * 16 + lane] = cs;
            #pragma unroll
            for (int os = 0; os < 4; ++os)
                #pragma unroll
                for (int r = 0; r < 4; ++r) {
                    const float v = accY[g][os][r] +
                        cmb[((mh * 16 + g * 4 + os) * 4 + r) * 64 + lane];
                    yp[(size_t)(b * C2_ + os * 16 + quad * 4 + r) * N_ + m_wave + g * 16 + col] = v;
                }
        }
    }
}

// ---------------------------------------------------------------------------
// K4: fused partial-combine + w_t GEMM (MFMA) + BN partial stats.
//     32-n tiles, grid (128, 8) = 1024 blocks (4/CU) for latency overlap.
//     Per (b, 32-n tile): cinv = 1/(eps+sum cspart); d = xc - (y0+y1+y2)*cinv
//     staged TRANSPOSED to LDS bf16 d_t[n][72]; w_t staged bf16 [o][72].
//     Wave = o-tile; K = 64 -> kt in [0,2).  t = acc + b_t -> t_buf;
//     per-block channel partial sums/sumsq -> part_bn[c][blk].
//     NOTE: reads y1 region == writes t_buf region; all reads complete
//     before the post-staging barrier, writes only after (same tile only).
// ---------------------------------------------------------------------------
__global__ __launch_bounds__(256) void k4_t(
    const float* __restrict__ xc, const float* __restrict__ y0,
    const float* __restrict__ y1, const float* __restrict__ y2,
    const float* __restrict__ cspart, const float* __restrict__ w_t,
    const float* __restrict__ b_t, float* __restrict__ t_buf,
    float* __restrict__ part_bn)
{
    __shared__ __align__(16) unsigned short wlds[64 * 72];
    __shared__ __align__(16) unsigned short d_t[32 * 72];
    __shared__ float cinv[32];
    const int tid = threadIdx.x;
    const int wave = tid >> 6, lane = tid & 63;
    const int quad = lane >> 4, col = lane & 15;
    const int b = blockIdx.y;
    const int n0 = blockIdx.x * 32;
    const size_t base = (size_t)b * C2_ * N_;

    // phase 0: w_t -> bf16 LDS; per-n colsum inverse
    #pragma unroll
    for (int it = 0; it < 4; ++it) {
        const int idx4 = it * 256 + tid;               // [0, 1024)
        const int o = idx4 >> 4, i4 = (idx4 & 15) * 4;
        const float4 v = *(const float4*)(w_t + o * 64 + i4);
        us4 pk;
        pk.a = f2bf(v.x); pk.b = f2bf(v.y); pk.c = f2bf(v.z); pk.d = f2bf(v.w);
        *(us4*)&wlds[o * 72 + i4] = pk;
    }
    if (tid < 32) {
        const int n = n0 + tid;
        const float cs = cspart[(size_t)b * N_ + n] + cspart[(size_t)(8 + b) * N_ + n]
                       + cspart[(size_t)(16 + b) * N_ + n];
        cinv[tid] = 1.0f / (1e-9f + cs);
    }
    __syncthreads();

    // phase 1: d = xc - (y0+y1+y2)*cinv, transposed bf16 -> d_t[n][i]
    #pragma unroll
    for (int it = 0; it < 2; ++it) {
        const int idx4 = it * 256 + tid;               // [0, 512)
        const int i = idx4 >> 3, n4 = (idx4 & 7) * 4;
        const size_t g = base + (size_t)i * N_ + n0 + n4;
        const float4 c4 = *(const float4*)(xc + g);
        const float4 a0 = *(const float4*)(y0 + g);
        const float4 a1 = *(const float4*)(y1 + g);
        const float4 a2 = *(const float4*)(y2 + g);
        d_t[(n4 + 0) * 72 + i] = f2bf(c4.x - (a0.x + a1.x + a2.x) * cinv[n4 + 0]);
        d_t[(n4 + 1) * 72 + i] = f2bf(c4.y - (a0.y + a1.y + a2.y) * cinv[n4 + 1]);
        d_t[(n4 + 2) * 72 + i] = f2bf(c4.z - (a0.z + a1.z + a2.z) * cinv[n4 + 2]);
        d_t[(n4 + 3) * 72 + i] = f2bf(c4.w - (a0.w + a1.w + a2.w) * cinv[n4 + 3]);
    }
    __syncthreads();

    const int ow = wave * 16;
    bf16x8 afr[2];
    #pragma unroll
    for (int kt = 0; kt < 2; ++kt)
        afr[kt] = *(const bf16x8*)&wlds[(ow + col) * 72 + kt * 32 + quad * 8];
    const float4 bt4 = *(const float4*)(b_t + ow + quad * 4);
    const float* btp = (const float*)&bt4;

    float s[4] = {0.f, 0.f, 0.f, 0.f}, q2[4] = {0.f, 0.f, 0.f, 0.f};
    #pragma unroll
    for (int ns = 0; ns < 2; ++ns) {
        f32x4 acc = {0.f, 0.f, 0.f, 0.f};
        #pragma unroll
        for (int kt = 0; kt < 2; ++kt) {
            const bf16x8 bfr = *(const bf16x8*)&d_t[(ns * 16 + col) * 72 + kt * 32 + quad * 8];
            acc = MFMA16(afr[kt], bfr, acc);
        }
        #pragma unroll
        for (int r = 0; r < 4; ++r) {
            const float t = acc[r] + btp[r];
            t_buf[base + (size_t)(ow + quad * 4 + r) * N_ + n0 + ns * 16 + col] = t;
            s[r] += t;
            q2[r] += t * t;
        }
    }
    #pragma unroll
    for (int r = 0; r < 4; ++r) {
        #pragma unroll
        for (int off = 1; off < 16; off <<= 1) {
            s[r]  += __shfl_xor(s[r],  off, 64);
            q2[r] += __shfl_xor(q2[r], off, 64);
        }
    }
    if (col == 0) {
        const int blk = blockIdx.x * 8 + b;            // [0, 1024)
        #pragma unroll
        for (int r = 0; r < 4; ++r) {
            part_bn[(size_t)(ow + quad * 4 + r) * 1024 + blk]      = s[r];
            part_bn[(size_t)(64 + ow + quad * 4 + r) * 1024 + blk] = q2[r];
        }
    }
}

// K5r: bn[c] = sum_blk part_bn[c][blk], c in [0,128)
__global__ __launch_bounds__(256) void k5r(
    const float* __restrict__ part_bn, float* __restrict__ bn)
{
    const int c = blockIdx.x;
    const int tid = threadIdx.x, wave = tid >> 6, lane = tid & 63;
    float s = 0.f;
    for (int j = tid; j < 1024; j += 256) s += part_bn[(size_t)c * 1024 + j];
    #pragma unroll
    for (int off = 1; off < 64; off <<= 1) s += __shfl_xor(s, off, 64);
    __shared__ float red[4];
    if (lane == 0) red[wave] = s;
    __syncthreads();
    if (tid == 0) bn[c] = red[0] + red[1] + red[2] + red[3];
}

// ---------------------------------------------------------------------------
// K6: out = xc + relu(gamma * (t - mean) * rsqrt(var + eps) + beta)
// ---------------------------------------------------------------------------
__global__ __launch_bounds__(256) void k6_out(
    const float* __restrict__ xc, const float* __restrict__ t_buf,
    const float* __restrict__ bn, const float* __restrict__ gamma,
    const float* __restrict__ beta, float* __restrict__ out)
{
    const int idx = blockIdx.x * 256 + threadIdx.x;
    const int o = (idx >> 10) & 63;
    const float invC = 1.0f / (float)(B_ * N_);
    const float mean = bn[o] * invC;
    const float var  = bn[64 + o] * invC - mean * mean;
    const float sc = gamma[o] * rsqrtf(var + 1e-5f);
    const float sh = beta[o] - mean * sc;
    const float4 t4 = ((const float4*)t_buf)[idx];
    const float4 c4 = ((const float4*)xc)[idx];
    float4 r;
    r.x = c4.x + fmaxf(0.f, sc * t4.x + sh);
    r.y = c4.y + fmaxf(0.f, sc * t4.y + sh);
    r.z = c4.z + fmaxf(0.f, sc * t4.z + sh);
    r.w = c4.w + fmaxf(0.f, sc * t4.w + sh);
    ((float4*)out)[idx] = r;
}

extern "C" void kernel_launch(void* const* d_in, const int* in_sizes, int n_in,
                              void* d_out, int out_size, void* d_ws, size_t ws_size,
                              hipStream_t stream) {
    const float* x     = (const float*)d_in[0];
    const float* w_qk  = (const float*)d_in[1];
    const float* w_v   = (const float*)d_in[2];
    const float* b_v   = (const float*)d_in[3];
    const float* w_x   = (const float*)d_in[4];
    const float* w_t   = (const float*)d_in[5];
    const float* b_t   = (const float*)d_in[6];
    const float* gamma = (const float*)d_in[7];
    const float* beta  = (const float*)d_in[8];
    float* out = (float*)d_out;

    char* ws = (char*)d_ws;
    unsigned short* qk_t  = (unsigned short*)ws;                      // 4 MB
    unsigned short* xv_bf = (unsigned short*)(ws + (4  << 20));       // 4 MB
    float* xc      = (float*)(ws + (8  << 20));                       // 8 MB
    float* yp0     = (float*)(ws + (16 << 20));                       // 8 MB
    float* tb_yp1  = (float*)(ws + (24 << 20));                       // 8 MB (ypart1, then t_buf)
    float* part_rs = (float*)(ws + (32 << 20));                       // 1 MB (k2 -> k2bc)
    float* cspart  = (float*)(ws + (32 << 20));                       // 384 KB (k3 -> k4; reuses part_rs)
    unsigned short* wbf = (unsigned short*)(ws + (33 << 20));         // 64 KB
    float* part_bn = (float*)(ws + (33 << 20) + (64 << 10));          // 512 KB
    float* bn      = (float*)(ws + (33 << 20) + (576 << 10));         // 512 B
    float* yp2     = out;                                             // 8 MB scratch until k4

    hipLaunchKernelGGL(k1_proj,     dim3(64, 8),  256, 0, stream,
                       x, w_qk, w_v, b_v, w_x, qk_t, xv_bf, xc);
    hipLaunchKernelGGL(k2_rowstats, dim3(1024),   256, 0, stream, qk_t, part_rs);
    hipLaunchKernelGGL(k2bc,        dim3(512),    256, 0, stream, part_rs, xv_bf, wbf);
    hipLaunchKernelGGL(k3_pv,       dim3(768),    256, 0, stream,
                       qk_t, xv_bf, wbf, yp0, tb_yp1, yp2, cspart);
    hipLaunchKernelGGL(k4_t,        dim3(128, 8), 256, 0, stream,
                       xc, yp0, tb_yp1, yp2, cspart, w_t, b_t, tb_yp1, part_bn);
    hipLaunchKernelGGL(k5r,         dim3(128),    256, 0, stream, part_bn, bn);
    hipLaunchKernelGGL(k6_out,      dim3(2048),   256, 0, stream, xc, tb_yp1, bn, gamma, beta, out);
}

// Round 12
// 166.494 us; speedup vs baseline: 1.3872x; 1.0331x over previous
//
#include <hip/hip_runtime.h>

#define B_   8
#define C_   128
#define N_   4096
#define C2_  64

typedef __bf16 bf16x8 __attribute__((ext_vector_type(8)));
typedef float  f32x4  __attribute__((ext_vector_type(4)));

#define MFMA16(a, b, c) __builtin_amdgcn_mfma_f32_16x16x32_bf16((a), (b), (c), 0, 0, 0)

// sqrt(log2(e)): fold into q/k so softmax uses exp2 directly (E' = E * log2e)
#define QK_SCALE 1.2011224087864498f

static __device__ __forceinline__ unsigned short f2bf(float f) {
    union { __bf16 b; unsigned short u; } cv;
    cv.b = (__bf16)f;
    return cv.u;
}
static __device__ __forceinline__ float bf2f(unsigned short u) {
    union { unsigned int u; float f; } cv;
    cv.u = ((unsigned int)u) << 16;
    return cv.f;
}

struct us4 { unsigned short a, b, c, d; };

// async global->LDS, 16 B per lane.  LDS dest must be linear in lane order.
static __device__ __forceinline__ void gl_lds16(const unsigned short* g, void* l) {
    __builtin_amdgcn_global_load_lds(
        (const __attribute__((address_space(1))) unsigned int*)g,
        (__attribute__((address_space(3))) unsigned int*)l,
        16, 0, 0);
}

// ---------------------------------------------------------------------------
// K1: fused projection GEMM.  D[192 o][64 n] = W(3x64 stacked)[o][c] * x[c][n]
//     per (b, 64-n tile).  Weights -> LDS bf16 [192][136]; x tile transposed
//     -> LDS bf16 x_t[64 n][136 c].  Epilogue: ot 0-3 -> qk_t (us4, *QK_SCALE);
//     ot 4-7 -> xv_bf (+b_v); ot 8-11 -> xc (f32).
// ---------------------------------------------------------------------------
__global__ __launch_bounds__(256) void k1_proj(
    const float* __restrict__ x, const float* __restrict__ w_qk,
    const float* __restrict__ w_v, const float* __restrict__ b_v,
    const float* __restrict__ w_x,
    unsigned short* __restrict__ qk_t, unsigned short* __restrict__ xv_bf,
    float* __restrict__ xc)
{
    __shared__ __align__(16) unsigned short w_lds[192 * 136];
    __shared__ __align__(16) unsigned short x_t[64 * 136];
    const int tid = threadIdx.x;
    const int wave = tid >> 6, lane = tid & 63;
    const int quad = lane >> 4, col = lane & 15;
    const int b = blockIdx.y;
    const int n0 = blockIdx.x * 64;

    const float* wsrc[3] = {w_qk, w_v, w_x};
    #pragma unroll
    for (int mat = 0; mat < 3; ++mat) {
        const float* wm = wsrc[mat];
        #pragma unroll
        for (int it = 0; it < 8; ++it) {
            const int idx = it * 256 + tid;            // [0, 2048)
            const int o = idx >> 5, c = (idx & 31) * 4;
            const float4 v = *(const float4*)(wm + o * C_ + c);
            us4 pk;
            pk.a = f2bf(v.x); pk.b = f2bf(v.y); pk.c = f2bf(v.z); pk.d = f2bf(v.w);
            *(us4*)&w_lds[(mat * 64 + o) * 136 + c] = pk;
        }
    }
    const float* xb = x + (size_t)b * C_ * N_ + n0;
    #pragma unroll
    for (int it = 0; it < 8; ++it) {
        const int idx = it * 256 + tid;                // [0, 2048)
        const int c = idx >> 4, n = (idx & 15) * 4;
        const float4 v = *(const float4*)(xb + (size_t)c * N_ + n);
        x_t[(n + 0) * 136 + c] = f2bf(v.x);
        x_t[(n + 1) * 136 + c] = f2bf(v.y);
        x_t[(n + 2) * 136 + c] = f2bf(v.z);
        x_t[(n + 3) * 136 + c] = f2bf(v.w);
    }
    __syncthreads();

    const int nw = wave * 16;
    bf16x8 bfr[4];
    #pragma unroll
    for (int kt = 0; kt < 4; ++kt)
        bfr[kt] = *(const bf16x8*)&x_t[(nw + col) * 136 + kt * 32 + quad * 8];

    const int n_g = n0 + nw + col;

    #pragma unroll
    for (int ot = 0; ot < 12; ++ot) {
        f32x4 acc = {0.f, 0.f, 0.f, 0.f};
        #pragma unroll
        for (int kt = 0; kt < 4; ++kt) {
            const bf16x8 afr = *(const bf16x8*)&w_lds[(ot * 16 + col) * 136 + kt * 32 + quad * 8];
            acc = MFMA16(afr, bfr[kt], acc);
        }
        if (ot < 4) {
            us4 pk;
            pk.a = f2bf(acc[0] * QK_SCALE); pk.b = f2bf(acc[1] * QK_SCALE);
            pk.c = f2bf(acc[2] * QK_SCALE); pk.d = f2bf(acc[3] * QK_SCALE);
            *(us4*)&qk_t[(size_t)(b * N_ + n_g) * C2_ + ot * 16 + quad * 4] = pk;
        } else if (ot < 8) {
            const float4 bv4 = *(const float4*)(b_v + (ot - 4) * 16 + quad * 4);
            const float* bvp = (const float*)&bv4;
            #pragma unroll
            for (int r = 0; r < 4; ++r)
                xv_bf[(size_t)(b * C2_ + (ot - 4) * 16 + quad * 4 + r) * N_ + n_g]
                    = f2bf(acc[r] + bvp[r]);
        } else {
            #pragma unroll
            for (int r = 0; r < 4; ++r)
                xc[(size_t)(b * C2_ + (ot - 8) * 16 + quad * 4 + r) * N_ + n_g] = acc[r];
        }
    }
}

// ---------------------------------------------------------------------------
// K2: partial row softmax sums.  Grid 2048: b=id&7, nblk=(id>>3)&31, mq=id>>8.
//     Wave owns 32 n-rows (2 A-frag sets); block owns 128 rows x 512 m as
//     4 chunks of 128 m (2x16 KB dbuf -> 5 blocks/CU).  part_rs[mq][b][n].
// ---------------------------------------------------------------------------
__global__ __launch_bounds__(256) void k2_rowstats(
    const unsigned short* __restrict__ qk_t, float* __restrict__ part_rs)
{
    __shared__ __align__(16) unsigned char lds_raw[2 * 16384];
    const int tid = threadIdx.x;
    const int wave = tid >> 6, lane = tid & 63;
    const int quad = lane >> 4, col = lane & 15;
    const int b = blockIdx.x & 7;
    const int nblk = (blockIdx.x >> 3) & 31;
    const int mq = blockIdx.x >> 8;                   // 0..7
    const int n_base = nblk * 128 + wave * 32;
    const int m_start = mq * 512;
    const unsigned short* qb = qk_t + (size_t)b * N_ * C2_;

    // two persistent A-frag sets: rows n_base + s*16 + col
    bf16x8 a0[2], a1[2];
    #pragma unroll
    for (int s = 0; s < 2; ++s) {
        const unsigned short* p = qb + (size_t)(n_base + s * 16 + col) * C2_ + quad * 8;
        a0[s] = *(const bf16x8*)p;
        a1[s] = *(const bf16x8*)(p + 32);
    }

    // stage 128 m-rows (16 KB) into buffer p
    auto stage = [&](int m0, int p) {
        unsigned char* base = lds_raw + p * 16384;
        #pragma unroll
        for (int r = 0; r < 4; ++r) {
            const int idx = r * 256 + tid;             // [0, 1024)
            const int row = idx >> 3, seg = idx & 7;
            gl_lds16(qb + (size_t)(m0 + row) * C2_ + (size_t)(seg ^ (row & 7)) * 8,
                     base + idx * 16);
        }
    };

    float run_s[2][4];
    #pragma unroll
    for (int s = 0; s < 2; ++s)
        #pragma unroll
        for (int r = 0; r < 4; ++r) run_s[s][r] = 0.f;

    stage(m_start, 0);
    __syncthreads();

    for (int c = 0; c < 4; ++c) {
        const int p = c & 1;
        if (c + 1 < 4) stage(m_start + (c + 1) * 128, 1 - p);
        const unsigned short* qt = (const unsigned short*)(lds_raw + p * 16384);
        #pragma unroll
        for (int ms = 0; ms < 8; ++ms) {
            const int row = ms * 16 + col;
            const bf16x8 b0 = *(const bf16x8*)(qt + row * 64 + ((quad ^ (col & 7)) * 8));
            const bf16x8 b1 = *(const bf16x8*)(qt + row * 64 + (((4 + quad) ^ (col & 7)) * 8));
            #pragma unroll
            for (int s = 0; s < 2; ++s) {
                f32x4 acc = {0.f, 0.f, 0.f, 0.f};
                acc = MFMA16(a0[s], b0, acc);
                acc = MFMA16(a1[s], b1, acc);
                #pragma unroll
                for (int r = 0; r < 4; ++r)
                    run_s[s][r] += __builtin_amdgcn_exp2f(acc[r]);
            }
        }
        __syncthreads();
    }

    #pragma unroll
    for (int s = 0; s < 2; ++s)
        #pragma unroll
        for (int r = 0; r < 4; ++r) {
            #pragma unroll
            for (int off = 1; off < 16; off <<= 1)
                run_s[s][r] += __shfl_xor(run_s[s][r], off, 64);
        }
    if (col == 0) {
        #pragma unroll
        for (int s = 0; s < 2; ++s)
            #pragma unroll
            for (int r = 0; r < 4; ++r)
                part_rs[((size_t)(mq * 8 + b) << 12) + n_base + s * 16 + quad * 4 + r]
                    = run_s[s][r];
    }
}

// ---------------------------------------------------------------------------
// K2bc: fused rowsum-combine + xv scale.  Grid 512: b=id&7, nt=id>>3.
//       winv = 1/rowsum (LDS-local); wbf = bf16(winv); xv *= winv in place.
// ---------------------------------------------------------------------------
__global__ __launch_bounds__(256) void k2bc(
    const float* __restrict__ part_rs, unsigned short* __restrict__ xv_bf,
    unsigned short* __restrict__ wbf)
{
    __shared__ float wl[64];
    const int tid = threadIdx.x;
    const int b = blockIdx.x & 7;
    const int n0 = (blockIdx.x >> 3) * 64;
    if (tid < 64) {
        float s = 0.f;
        #pragma unroll
        for (int q = 0; q < 8; ++q)
            s += part_rs[((size_t)(q * 8 + b) << 12) + n0 + tid];
        const float w = 1.0f / s;
        wl[tid] = w;
        wbf[b * N_ + n0 + tid] = f2bf(w);
    }
    __syncthreads();
    #pragma unroll
    for (int it = 0; it < 4; ++it) {
        const int idx4 = it * 256 + tid;               // [0, 1024)
        const int o = idx4 >> 4, n4 = (idx4 & 15) * 4;
        unsigned short* p = xv_bf + (size_t)(b * C2_ + o) * N_ + n0 + n4;
        us4 v = *(us4*)p;
        v.a = f2bf(bf2f(v.a) * wl[n4 + 0]);
        v.b = f2bf(bf2f(v.b) * wl[n4 + 1]);
        v.c = f2bf(bf2f(v.c) * wl[n4 + 2]);
        v.d = f2bf(bf2f(v.d) * wl[n4 + 3]);
        *(us4*)p = v;
    }
}

// ---------------------------------------------------------------------------
// K3: block owns 128 m-cols and a THIRD of n (split-K, grid 768, 3 blk/CU).
//     Waves: (m-half mh, n-half nh2).  Per 64-n chunk: stage qk slab + xv tile
//     (dbuf DMA); each wave computes E for its 32 n x 64 m; S' = exp2(E)
//     (row-normalizer pre-folded into xv); LDS round-trip; PV MFMA + colsum
//     MFMA (A-rows = wbf).  Epilogue: cross n-half combine in LDS; write
//     partial Y (BF16) + partial colsum (f32); k4 combines the 3 splits.
// ---------------------------------------------------------------------------
__global__ __launch_bounds__(256, 3) void k3_pv(
    const unsigned short* __restrict__ qk_t, const unsigned short* __restrict__ xv_bf,
    const unsigned short* __restrict__ wbf,
    unsigned short* __restrict__ yb0, unsigned short* __restrict__ yb1,
    unsigned short* __restrict__ yb2, float* __restrict__ cspart)
{
    // 0..16K: qk dbuf | 16K..32K: xv dbuf | 32K..52K: S tiles (4 waves x [4g][16][40])
    __shared__ __align__(16) unsigned char lds_raw[32768 + 4 * 5120];
    const int tid = threadIdx.x;
    const int wave = tid >> 6, lane = tid & 63;
    const int quad = lane >> 4, col = lane & 15;
    const int nh2 = wave & 1, mh = wave >> 1;
    const int b = blockIdx.x & 7;
    const int m_blk = ((blockIdx.x >> 3) & 31) * 128;
    const int sk = blockIdx.x >> 8;                  // 0..2 (split-K index)
    const int n_start = (sk == 0) ? 0 : 1408 + (sk - 1) * 1344;
    const int n_chunks = (sk == 0) ? 22 : 21;
    const int m_wave = m_blk + mh * 64;
    const unsigned short* qb = qk_t + (size_t)b * N_ * C2_;
    const unsigned short* vb = xv_bf + (size_t)b * C2_ * N_;
    const unsigned short* wb = wbf + b * N_;
    unsigned short* yp = (sk == 0) ? yb0 : (sk == 1) ? yb1 : yb2;

    // persistent B-operands for E: this wave's 64 m-cols (4 groups of 16)
    bf16x8 kb0[4], kb1[4];
    #pragma unroll
    for (int g = 0; g < 4; ++g) {
        const unsigned short* p = qb + (size_t)(m_wave + g * 16 + col) * C2_ + quad * 8;
        kb0[g] = *(const bf16x8*)p;
        kb1[g] = *(const bf16x8*)(p + 32);
    }

    unsigned short* stS = (unsigned short*)(lds_raw + 32768 + wave * 5120); // [g][col][40]

    auto stage = [&](int n0, int p) {
        unsigned char* qbase = lds_raw + p * 8192;
        unsigned char* vbase = lds_raw + 16384 + p * 8192;
        #pragma unroll
        for (int r = 0; r < 2; ++r) {
            const int idx = r * 256 + tid;
            const int row = idx >> 3, seg = idx & 7;
            const int ss = seg ^ (row & 7);
            gl_lds16(qb + (size_t)(n0 + row) * C2_ + (size_t)ss * 8, qbase + idx * 16);
            gl_lds16(vb + (size_t)row * N_ + n0 + ss * 8, vbase + idx * 16);
        }
    };

    f32x4 accY[4][4];
    #pragma unroll
    for (int g = 0; g < 4; ++g)
        #pragma unroll
        for (int os = 0; os < 4; ++os) accY[g][os] = (f32x4){0.f, 0.f, 0.f, 0.f};
    f32x4 csacc[4];
    #pragma unroll
    for (int g = 0; g < 4; ++g) csacc[g] = (f32x4){0.f, 0.f, 0.f, 0.f};

    stage(n_start, 0);
    __syncthreads();

    for (int c = 0; c < n_chunks; ++c) {
        const int n0 = n_start + c * 64;
        const int p = c & 1;
        if (c + 1 < n_chunks) stage(n0 + 64, 1 - p);

        const unsigned short* qt = (const unsigned short*)(lds_raw + p * 8192);
        const unsigned short* vt = (const unsigned short*)(lds_raw + 16384 + p * 8192);

        // colsum weight fragment for this wave's 32-n slice (tiny L1 load)
        const bf16x8 wfrag = *(const bf16x8*)(wb + n0 + nh2 * 32 + quad * 8);

        // E phase over this wave's 32 n-rows; S' = exp2(E') straight to LDS
        #pragma unroll
        for (int ns = 0; ns < 2; ++ns) {
            const int row = nh2 * 32 + ns * 16 + col;
            const bf16x8 qa0 = *(const bf16x8*)(qt + row * 64 + ((quad ^ (col & 7)) * 8));
            const bf16x8 qa1 = *(const bf16x8*)(qt + row * 64 + (((4 + quad) ^ (col & 7)) * 8));
            #pragma unroll
            for (int g = 0; g < 4; ++g) {
                f32x4 acc = {0.f, 0.f, 0.f, 0.f};
                acc = MFMA16(qa0, kb0[g], acc);
                acc = MFMA16(qa1, kb1[g], acc);
                union { unsigned short us[4]; uint2 u2; } pk;
                #pragma unroll
                for (int r = 0; r < 4; ++r)
                    pk.us[r] = f2bf(__builtin_amdgcn_exp2f(acc[r]));
                *(uint2*)&stS[(g * 16 + col) * 40 + ns * 16 + quad * 4] = pk.u2;
            }
        }

        // same-wave round-trip: S' as B-operand (K = this wave's 32 n)
        bf16x8 sB[4];
        #pragma unroll
        for (int g = 0; g < 4; ++g)
            sB[g] = *(const bf16x8*)&stS[(g * 16 + col) * 40 + quad * 8];

        // colsum via MFMA: A rows all = w  ->  D rows all = colsum
        #pragma unroll
        for (int g = 0; g < 4; ++g)
            csacc[g] = MFMA16(wfrag, sB[g], csacc[g]);

        // PV: A = xv rows (o), k = this wave's 32 n
        #pragma unroll
        for (int os = 0; os < 4; ++os) {
            const bf16x8 va = *(const bf16x8*)(vt + (os * 16 + col) * 64 +
                                               (((nh2 * 4 + quad) ^ (col & 7)) * 8));
            #pragma unroll
            for (int g = 0; g < 4; ++g)
                accY[g][os] = MFMA16(va, sB[g], accY[g][os]);
        }
        __syncthreads();
    }

    // epilogue: combine the two n-halves (waves nh2=1 -> LDS; nh2=0 adds+writes)
    float* cmb = (float*)lds_raw;              // 32 KB: [mh][g*4+os][r][lane]
    float* csc = (float*)(lds_raw + 32768);    // 2 KB:  [mh][g][lane]
    if (nh2 == 1) {
        #pragma unroll
        for (int g = 0; g < 4; ++g) {
            #pragma unroll
            for (int os = 0; os < 4; ++os)
                #pragma unroll
                for (int r = 0; r < 4; ++r)
                    cmb[((mh * 16 + g * 4 + os) * 4 + r) * 64 + lane] = accY[g][os][r];
            csc[(mh * 4 + g) * 64 + lane] = csacc[g][0];
        }
    }
    __syncthreads();
    if (nh2 == 0) {
        #pragma unroll
        for (int g = 0; g < 4; ++g) {
            const float cs = csacc[g][0] + csc[(mh * 4 + g) * 64 + lane];
            if (lane < 16)
                cspart[((size_t)sk * 8 + b) * N_ + m_wave + g * 16 + lane] = cs;
            #pragma unroll
            for (int os = 0; os < 4; ++os)
                #pragma unroll
                for (int r = 0; r < 4; ++r) {
                    const float v = accY[g][os][r] +
                        cmb[((mh * 16 + g * 4 + os) * 4 + r) * 64 + lane];
                    yp[(size_t)(b * C2_ + os * 16 + quad * 4 + r) * N_ + m_wave + g * 16 + col]
                        = f2bf(v);
                }
        }
    }
}

// ---------------------------------------------------------------------------
// K4: fused partial-combine + w_t GEMM (MFMA) + BN partial stats.
//     Grid (64, 8), 64-n tiles.  cinv = 1/(eps+sum cspart);
//     d = xc - (y0+y1+y2)*cinv (y partials BF16 -> 12 MB read, not 24)
//     staged TRANSPOSED to LDS bf16 d_t[n][72]; w_t staged bf16 [o][72].
//     Wave = o-tile; K = 64 -> kt in [0,2).  t = acc + b_t -> t_buf;
//     per-block channel partial sums/sumsq -> part_bn[c][blk].
// ---------------------------------------------------------------------------
__global__ __launch_bounds__(256) void k4_t(
    const float* __restrict__ xc, const unsigned short* __restrict__ y0,
    const unsigned short* __restrict__ y1, const unsigned short* __restrict__ y2,
    const float* __restrict__ cspart, const float* __restrict__ w_t,
    const float* __restrict__ b_t, float* __restrict__ t_buf,
    float* __restrict__ part_bn)
{
    __shared__ __align__(16) unsigned short wlds[64 * 72];
    __shared__ __align__(16) unsigned short d_t[64 * 72];
    __shared__ float cinv[64];
    const int tid = threadIdx.x;
    const int wave = tid >> 6, lane = tid & 63;
    const int quad = lane >> 4, col = lane & 15;
    const int b = blockIdx.y;
    const int n0 = blockIdx.x * 64;
    const size_t base = (size_t)b * C2_ * N_;

    // phase 0: w_t -> bf16 LDS; per-n colsum inverse
    #pragma unroll
    for (int it = 0; it < 4; ++it) {
        const int idx4 = it * 256 + tid;               // [0, 1024)
        const int o = idx4 >> 4, i4 = (idx4 & 15) * 4;
        const float4 v = *(const float4*)(w_t + o * 64 + i4);
        us4 pk;
        pk.a = f2bf(v.x); pk.b = f2bf(v.y); pk.c = f2bf(v.z); pk.d = f2bf(v.w);
        *(us4*)&wlds[o * 72 + i4] = pk;
    }
    if (tid < 64) {
        const int n = n0 + tid;
        const float cs = cspart[(size_t)b * N_ + n] + cspart[(size_t)(8 + b) * N_ + n]
                       + cspart[(size_t)(16 + b) * N_ + n];
        cinv[tid] = 1.0f / (1e-9f + cs);
    }
    __syncthreads();

    // phase 1: d = xc - (y0+y1+y2)*cinv, transposed bf16 -> d_t[n][i]
    #pragma unroll
    for (int it = 0; it < 4; ++it) {
        const int idx4 = it * 256 + tid;               // [0, 1024)
        const int i = idx4 >> 4, n4 = (idx4 & 15) * 4;
        const size_t g = base + (size_t)i * N_ + n0 + n4;
        const float4 c4 = *(const float4*)(xc + g);
        const us4 u0 = *(const us4*)(y0 + g);
        const us4 u1 = *(const us4*)(y1 + g);
        const us4 u2 = *(const us4*)(y2 + g);
        d_t[(n4 + 0) * 72 + i] = f2bf(c4.x - (bf2f(u0.a) + bf2f(u1.a) + bf2f(u2.a)) * cinv[n4 + 0]);
        d_t[(n4 + 1) * 72 + i] = f2bf(c4.y - (bf2f(u0.b) + bf2f(u1.b) + bf2f(u2.b)) * cinv[n4 + 1]);
        d_t[(n4 + 2) * 72 + i] = f2bf(c4.z - (bf2f(u0.c) + bf2f(u1.c) + bf2f(u2.c)) * cinv[n4 + 2]);
        d_t[(n4 + 3) * 72 + i] = f2bf(c4.w - (bf2f(u0.d) + bf2f(u1.d) + bf2f(u2.d)) * cinv[n4 + 3]);
    }
    __syncthreads();

    const int ow = wave * 16;
    bf16x8 afr[2];
    #pragma unroll
    for (int kt = 0; kt < 2; ++kt)
        afr[kt] = *(const bf16x8*)&wlds[(ow + col) * 72 + kt * 32 + quad * 8];
    const float4 bt4 = *(const float4*)(b_t + ow + quad * 4);
    const float* btp = (const float*)&bt4;

    float s[4] = {0.f, 0.f, 0.f, 0.f}, q2[4] = {0.f, 0.f, 0.f, 0.f};
    #pragma unroll
    for (int ns = 0; ns < 4; ++ns) {
        f32x4 acc = {0.f, 0.f, 0.f, 0.f};
        #pragma unroll
        for (int kt = 0; kt < 2; ++kt) {
            const bf16x8 bfr = *(const bf16x8*)&d_t[(ns * 16 + col) * 72 + kt * 32 + quad * 8];
            acc = MFMA16(afr[kt], bfr, acc);
        }
        #pragma unroll
        for (int r = 0; r < 4; ++r) {
            const float t = acc[r] + btp[r];
            t_buf[base + (size_t)(ow + quad * 4 + r) * N_ + n0 + ns * 16 + col] = t;
            s[r] += t;
            q2[r] += t * t;
        }
    }
    #pragma unroll
    for (int r = 0; r < 4; ++r) {
        #pragma unroll
        for (int off = 1; off < 16; off <<= 1) {
            s[r]  += __shfl_xor(s[r],  off, 64);
            q2[r] += __shfl_xor(q2[r], off, 64);
        }
    }
    if (col == 0) {
        const int blk = blockIdx.x * 8 + b;            // [0, 512)
        #pragma unroll
        for (int r = 0; r < 4; ++r) {
            part_bn[(size_t)(ow + quad * 4 + r) * 512 + blk]      = s[r];
            part_bn[(size_t)(64 + ow + quad * 4 + r) * 512 + blk] = q2[r];
        }
    }
}

// K5r: bn[c] = sum_blk part_bn[c][blk], c in [0,128)
__global__ __launch_bounds__(256) void k5r(
    const float* __restrict__ part_bn, float* __restrict__ bn)
{
    const int c = blockIdx.x;
    const int tid = threadIdx.x, wave = tid >> 6, lane = tid & 63;
    float s = 0.f;
    for (int j = tid; j < 512; j += 256) s += part_bn[(size_t)c * 512 + j];
    #pragma unroll
    for (int off = 1; off < 64; off <<= 1) s += __shfl_xor(s, off, 64);
    __shared__ float red[4];
    if (lane == 0) red[wave] = s;
    __syncthreads();
    if (tid == 0) bn[c] = red[0] + red[1] + red[2] + red[3];
}

// ---------------------------------------------------------------------------
// K6: out = xc + relu(gamma * (t - mean) * rsqrt(var + eps) + beta)
// ---------------------------------------------------------------------------
__global__ __launch_bounds__(256) void k6_out(
    const float* __restrict__ xc, const float* __restrict__ t_buf,
    const float* __restrict__ bn, const float* __restrict__ gamma,
    const float* __restrict__ beta, float* __restrict__ out)
{
    const int idx = blockIdx.x * 256 + threadIdx.x;
    const int o = (idx >> 10) & 63;
    const float invC = 1.0f / (float)(B_ * N_);
    const float mean = bn[o] * invC;
    const float var  = bn[64 + o] * invC - mean * mean;
    const float sc = gamma[o] * rsqrtf(var + 1e-5f);
    const float sh = beta[o] - mean * sc;
    const float4 t4 = ((const float4*)t_buf)[idx];
    const float4 c4 = ((const float4*)xc)[idx];
    float4 r;
    r.x = c4.x + fmaxf(0.f, sc * t4.x + sh);
    r.y = c4.y + fmaxf(0.f, sc * t4.y + sh);
    r.z = c4.z + fmaxf(0.f, sc * t4.z + sh);
    r.w = c4.w + fmaxf(0.f, sc * t4.w + sh);
    ((float4*)out)[idx] = r;
}

extern "C" void kernel_launch(void* const* d_in, const int* in_sizes, int n_in,
                              void* d_out, int out_size, void* d_ws, size_t ws_size,
                              hipStream_t stream) {
    const float* x     = (const float*)d_in[0];
    const float* w_qk  = (const float*)d_in[1];
    const float* w_v   = (const float*)d_in[2];
    const float* b_v   = (const float*)d_in[3];
    const float* w_x   = (const float*)d_in[4];
    const float* w_t   = (const float*)d_in[5];
    const float* b_t   = (const float*)d_in[6];
    const float* gamma = (const float*)d_in[7];
    const float* beta  = (const float*)d_in[8];
    float* out = (float*)d_out;

    char* ws = (char*)d_ws;
    unsigned short* qk_t  = (unsigned short*)ws;                      // 4 MB
    unsigned short* xv_bf = (unsigned short*)(ws + (4  << 20));       // 4 MB
    float* xc      = (float*)(ws + (8  << 20));                       // 8 MB
    unsigned short* yb0 = (unsigned short*)(ws + (16 << 20));         // 4 MB (bf16 partial Y)
    unsigned short* yb1 = (unsigned short*)(ws + (20 << 20));         // 4 MB (bf16 partial Y)
    float* t_buf   = (float*)(ws + (24 << 20));                       // 8 MB
    float* part_rs = (float*)(ws + (32 << 20));                       // 1 MB (k2 -> k2bc)
    float* cspart  = (float*)(ws + (32 << 20));                       // 384 KB (k3 -> k4; reuses part_rs)
    unsigned short* wbf = (unsigned short*)(ws + (33 << 20));         // 64 KB
    float* part_bn = (float*)(ws + (33 << 20) + (64 << 10));          // 256 KB
    float* bn      = (float*)(ws + (33 << 20) + (320 << 10));         // 512 B
    unsigned short* yb2 = (unsigned short*)out;                       // 4 MB bf16 scratch until k4

    hipLaunchKernelGGL(k1_proj,     dim3(64, 8),  256, 0, stream,
                       x, w_qk, w_v, b_v, w_x, qk_t, xv_bf, xc);
    hipLaunchKernelGGL(k2_rowstats, dim3(2048),   256, 0, stream, qk_t, part_rs);
    hipLaunchKernelGGL(k2bc,        dim3(512),    256, 0, stream, part_rs, xv_bf, wbf);
    hipLaunchKernelGGL(k3_pv,       dim3(768),    256, 0, stream,
                       qk_t, xv_bf, wbf, yb0, yb1, yb2, cspart);
    hipLaunchKernelGGL(k4_t,        dim3(64, 8),  256, 0, stream,
                       xc, yb0, yb1, yb2, cspart, w_t, b_t, t_buf, part_bn);
    hipLaunchKernelGGL(k5r,         dim3(128),    256, 0, stream, part_bn, bn);
    hipLaunchKernelGGL(k6_out,      dim3(2048),   256, 0, stream, xc, t_buf, bn, gamma, beta, out);
}